// Round 1
// baseline (1245.334 us; speedup 1.0000x reference)
//
#include <hip/hip_runtime.h>
#include <hip/hip_bf16.h>
#include <math.h>

// ConformHopfieldBatch: B=4 S=2048 IN=64 D=128 HID=400 H=4 K=20 NQ=18
// Key insight: softmax is monotone -> top_k(assoc) == top_k(raw scores); assoc
// values are never output, so softmax (and the 1/sqrt(D) scale) is skipped.
// All math fp32 (no fp32 MFMA on CDNA4; bf16 would perturb scores ~2e-2 vs
// rank-20/21 gaps ~6e-3 and corrupt the selected set).

#define SS 2048
#define NBATCH 4

__constant__ float c_alphas[18] = {0.05f,0.06f,0.08f,0.1f,0.12f,0.14f,0.15f,0.17f,
                                   0.19f,0.2f,0.21f,0.23f,0.25f,0.3f,0.35f,0.38f,0.4f,0.45f};

// output flat offsets (return-order concat)
#define OFF_Y      1
#define OFF_YPRED  32769
#define OFF_YLOW   65537ll
#define OFF_YHIGH  655361ll
#define OFF_ERR    1245185ll
#define OFF_QLOW   1253377ll
#define OFF_QHIGH  1843201ll

// ---------------------------------------------------------------------------
// Kernel A: fused MLP(64->400->400->400->128) + LayerNorm + projection(128->512)
// 16 rows per block, 256 threads. blocks 0..511: X_ctx_true -> q; 512..1023: sim -> k.
// Each weight element is read exactly once per block (all 16 rows live in one thread's
// accumulators), activations stay in LDS (55KB -> 2 blocks/CU).
// ---------------------------------------------------------------------------
__global__ __launch_bounds__(256) void k_mlp(
    const float* __restrict__ Xt, const float* __restrict__ Xs,
    const float* __restrict__ W1, const float* __restrict__ b1,
    const float* __restrict__ W2, const float* __restrict__ b2,
    const float* __restrict__ W3, const float* __restrict__ b3,
    const float* __restrict__ W4, const float* __restrict__ b4,
    const float* __restrict__ Wq, const float* __restrict__ bq,
    const float* __restrict__ Wk, const float* __restrict__ bk,
    const float* __restrict__ g_q, const float* __restrict__ beta_q,
    const float* __restrict__ g_k, const float* __restrict__ beta_k,
    float* __restrict__ qout, float* __restrict__ kout)
{
    __shared__ float xa[16*64];    // 4KB
    __shared__ float hA[16*400];   // 25.6KB
    __shared__ float hB[16*400];   // 25.6KB

    const int tid  = threadIdx.x;
    const int half = (blockIdx.x >= 512) ? 1 : 0;
    const int row0 = (blockIdx.x & 511) * 16;
    const float* X = half ? Xs : Xt;

    // stage 16 input rows (contiguous 1024 floats)
    {
        const float4* src = (const float4*)(X + (size_t)row0 * 64);
        ((float4*)xa)[tid] = src[tid];
    }
    __syncthreads();

    // ---- layer 1: K=64 -> N=400 (relu) ----
    {
        const int j0 = tid, j1 = tid + 256;
        const bool v1 = (j1 < 400);
        const int j1m = v1 ? j1 : j0;
        float acc0[16], acc1[16];
        #pragma unroll
        for (int r = 0; r < 16; ++r) { acc0[r] = 0.f; acc1[r] = 0.f; }
        #pragma unroll 4
        for (int i = 0; i < 64; ++i) {
            const float w0 = W1[i*400 + j0];
            const float w1 = W1[i*400 + j1m];
            #pragma unroll
            for (int r = 0; r < 16; ++r) {
                const float x = xa[r*64 + i];
                acc0[r] = fmaf(x, w0, acc0[r]);
                acc1[r] = fmaf(x, w1, acc1[r]);
            }
        }
        const float bb0 = b1[j0], bb1 = b1[j1m];
        #pragma unroll
        for (int r = 0; r < 16; ++r) {
            hA[r*400 + j0] = fmaxf(acc0[r] + bb0, 0.f);
            if (v1) hA[r*400 + j1] = fmaxf(acc1[r] + bb1, 0.f);
        }
    }
    __syncthreads();

    // ---- layer 2: 400 -> 400 (relu), hA -> hB ----
    {
        const int j0 = tid, j1 = tid + 256;
        const bool v1 = (j1 < 400);
        const int j1m = v1 ? j1 : j0;
        float acc0[16], acc1[16];
        #pragma unroll
        for (int r = 0; r < 16; ++r) { acc0[r] = 0.f; acc1[r] = 0.f; }
        #pragma unroll 4
        for (int i = 0; i < 400; ++i) {
            const float w0 = W2[i*400 + j0];
            const float w1 = W2[i*400 + j1m];
            #pragma unroll
            for (int r = 0; r < 16; ++r) {
                const float x = hA[r*400 + i];
                acc0[r] = fmaf(x, w0, acc0[r]);
                acc1[r] = fmaf(x, w1, acc1[r]);
            }
        }
        const float bb0 = b2[j0], bb1 = b2[j1m];
        #pragma unroll
        for (int r = 0; r < 16; ++r) {
            hB[r*400 + j0] = fmaxf(acc0[r] + bb0, 0.f);
            if (v1) hB[r*400 + j1] = fmaxf(acc1[r] + bb1, 0.f);
        }
    }
    __syncthreads();

    // ---- layer 3: 400 -> 400 (relu), hB -> hA ----
    {
        const int j0 = tid, j1 = tid + 256;
        const bool v1 = (j1 < 400);
        const int j1m = v1 ? j1 : j0;
        float acc0[16], acc1[16];
        #pragma unroll
        for (int r = 0; r < 16; ++r) { acc0[r] = 0.f; acc1[r] = 0.f; }
        #pragma unroll 4
        for (int i = 0; i < 400; ++i) {
            const float w0 = W3[i*400 + j0];
            const float w1 = W3[i*400 + j1m];
            #pragma unroll
            for (int r = 0; r < 16; ++r) {
                const float x = hB[r*400 + i];
                acc0[r] = fmaf(x, w0, acc0[r]);
                acc1[r] = fmaf(x, w1, acc1[r]);
            }
        }
        const float bb0 = b3[j0], bb1 = b3[j1m];
        #pragma unroll
        for (int r = 0; r < 16; ++r) {
            hA[r*400 + j0] = fmaxf(acc0[r] + bb0, 0.f);
            if (v1) hA[r*400 + j1] = fmaxf(acc1[r] + bb1, 0.f);
        }
    }
    __syncthreads();

    // ---- layer 4: 400 -> 128 (no relu), hA -> hB (enc, stride 128) ----
    {
        const int j  = tid & 127;
        const int r0 = (tid >> 7) * 8;
        float acc[8];
        #pragma unroll
        for (int r = 0; r < 8; ++r) acc[r] = 0.f;
        #pragma unroll 4
        for (int i = 0; i < 400; ++i) {
            const float w = W4[i*128 + j];
            #pragma unroll
            for (int r = 0; r < 8; ++r)
                acc[r] = fmaf(hA[(r0+r)*400 + i], w, acc[r]);
        }
        const float bb = b4[j];
        #pragma unroll
        for (int r = 0; r < 8; ++r)
            hB[(r0+r)*128 + j] = acc[r] + bb;
    }
    __syncthreads();

    // ---- LayerNorm (two-pass, matches jnp mean/var) -> hA (stride 128) ----
    {
        const float* g  = half ? g_k : g_q;
        const float* be = half ? beta_k : beta_q;
        const int lane = tid & 63;
        const int wg   = tid >> 6;
        const float gl0 = g[lane],  gl1 = g[lane+64];
        const float bl0 = be[lane], bl1 = be[lane+64];
        #pragma unroll 1
        for (int d = 0; d < 4; ++d) {
            const int r = wg*4 + d;
            const float v0 = hB[r*128 + lane];
            const float v1 = hB[r*128 + lane + 64];
            float s = v0 + v1;
            #pragma unroll
            for (int o = 32; o > 0; o >>= 1) s += __shfl_xor(s, o);
            const float mu = s * (1.f/128.f);
            const float d0 = v0 - mu, d1 = v1 - mu;
            float vs = d0*d0 + d1*d1;
            #pragma unroll
            for (int o = 32; o > 0; o >>= 1) vs += __shfl_xor(vs, o);
            const float rstd = rsqrtf(vs * (1.f/128.f) + 1e-5f);
            hA[r*128 + lane]      = d0*rstd*gl0 + bl0;
            hA[r*128 + lane + 64] = d1*rstd*gl1 + bl1;
        }
    }
    __syncthreads();

    // ---- projection: 128 -> 512, write q or k (row stride 512) ----
    {
        const float* Wp = half ? Wk : Wq;
        const float* bp = half ? bk : bq;
        float* outp = (half ? kout : qout) + (size_t)row0 * 512;
        const int j0 = tid, j1 = tid + 256;
        float acc0[16], acc1[16];
        #pragma unroll
        for (int r = 0; r < 16; ++r) { acc0[r] = 0.f; acc1[r] = 0.f; }
        #pragma unroll 4
        for (int i = 0; i < 128; ++i) {
            const float w0 = Wp[i*512 + j0];
            const float w1 = Wp[i*512 + j1];
            #pragma unroll
            for (int r = 0; r < 16; ++r) {
                const float x = hA[r*128 + i];
                acc0[r] = fmaf(x, w0, acc0[r]);
                acc1[r] = fmaf(x, w1, acc1[r]);
            }
        }
        const float bb0 = bp[j0], bb1 = bp[j1];
        #pragma unroll
        for (int r = 0; r < 16; ++r) {
            outp[(size_t)r*512 + j0] = acc0[r] + bb0;
            outp[(size_t)r*512 + j1] = acc1[r] + bb1;
        }
    }
}

// ---------------------------------------------------------------------------
// Kernel B: fused scores (q@k^T per (b,h)) + streaming top-20 + quantiles.
// Block = (stile, h, b): 64 q-rows vs full m-range (32 tiles of 64), K chunked
// by 32 (LDS 64.2KB -> fits 64KB static limit, 2 blocks/CU if 160KB avail).
// Per-thread top-20 lists: 4 slots per row (tid&63 = row, tid>>6 = slot).
// ---------------------------------------------------------------------------
__global__ __launch_bounds__(256) void k_scores_topk(
    const float* __restrict__ qbuf, const float* __restrict__ kbuf,
    const float* __restrict__ errors, const float* __restrict__ y,
    const float* __restrict__ y_pred,
    float* __restrict__ out, float* __restrict__ hacc)
{
    __shared__ float Qs[64*33];            // 8448B (stride 33: conflict-free)
    __shared__ float Ks[64*33];            // 8448B
    __shared__ float st[64*65];            // 16640B score tile (stride 65)
    __shared__ float lv[64*4*20];          // 20480B list values (desc)
    __shared__ unsigned short lc[64*4*20]; // 10240B list cols

    const int tid   = threadIdx.x;
    const int stile = blockIdx.x;   // 0..31
    const int h     = blockIdx.y;   // 0..3
    const int b     = blockIdx.z;   // 0..3

    for (int u = tid; u < 64*4*20; u += 256) { lv[u] = -INFINITY; lc[u] = 0; }

    const int myr   = tid & 63;
    const int slot  = tid >> 6;
    const int lbase = (myr*4 + slot)*20;
    float lmin = -INFINITY;
    const int sg_my = stile*64 + myr;

    const int tx = tid & 15;
    const int ty = tid >> 4;

    const float* qsrc = qbuf + ((size_t)(b*SS + stile*64))*512 + h*128;

    for (int mt = 0; mt < 32; ++mt) {
        const float* ksrc = kbuf + ((size_t)(b*SS + mt*64))*512 + h*128;
        float acc[4][4];
        #pragma unroll
        for (int d = 0; d < 4; ++d)
            #pragma unroll
            for (int e = 0; e < 4; ++e) acc[d][e] = 0.f;

        for (int kc = 0; kc < 4; ++kc) {
            __syncthreads();   // prev readers of Qs/Ks/st done
            #pragma unroll
            for (int u = 0; u < 2; ++u) {
                const int f = tid + 256*u;
                const int r = f >> 3, i4 = (f & 7)*4;
                const float4 v = *(const float4*)(qsrc + (size_t)r*512 + kc*32 + i4);
                float* dst = &Qs[r*33 + i4];
                dst[0]=v.x; dst[1]=v.y; dst[2]=v.z; dst[3]=v.w;
            }
            #pragma unroll
            for (int u = 0; u < 2; ++u) {
                const int f = tid + 256*u;
                const int r = f >> 3, i4 = (f & 7)*4;
                const float4 v = *(const float4*)(ksrc + (size_t)r*512 + kc*32 + i4);
                float* dst = &Ks[r*33 + i4];
                dst[0]=v.x; dst[1]=v.y; dst[2]=v.z; dst[3]=v.w;
            }
            __syncthreads();
            const float* qb = &Qs[(ty*4)*33];
            const float* kb = &Ks[(tx*4)*33];
            #pragma unroll 4
            for (int i = 0; i < 32; ++i) {
                float av[4], bv[4];
                #pragma unroll
                for (int d = 0; d < 4; ++d) av[d] = qb[d*33 + i];
                #pragma unroll
                for (int e = 0; e < 4; ++e) bv[e] = kb[e*33 + i];
                #pragma unroll
                for (int d = 0; d < 4; ++d)
                    #pragma unroll
                    for (int e = 0; e < 4; ++e)
                        acc[d][e] = fmaf(av[d], bv[e], acc[d][e]);
            }
        }
        #pragma unroll
        for (int d = 0; d < 4; ++d)
            #pragma unroll
            for (int e = 0; e < 4; ++e)
                st[(ty*4+d)*65 + tx*4+e] = acc[d][e];
        __syncthreads();

        // streaming top-20 update (scan order = increasing col -> stable ties)
        const int mbase = mt*64;
        for (int jj = 0; jj < 16; ++jj) {
            const int c = slot*16 + jj;
            const int m = mbase + c;
            const float v = st[myr*65 + c];
            if (m != sg_my && v > lmin) {          // skip diagonal; -inf init
                int n = 19;
                while (n > 0 && lv[lbase+n-1] < v) {
                    lv[lbase+n] = lv[lbase+n-1];
                    lc[lbase+n] = lc[lbase+n-1];
                    --n;
                }
                lv[lbase+n] = v;
                lc[lbase+n] = (unsigned short)m;
                lmin = lv[lbase+19];
            }
        }
    }
    __syncthreads();

    // epilogue: one thread per row (wave 0): merge 4 lists, gather errs,
    // sort 20, quantiles at beta and 1-beta, write 4 output blocks + score acc.
    if (tid < 64) {
        const int r  = tid;
        const int sg = stile*64 + r;
        const int base = r*80;
        int p0 = 0, p1 = 0, p2 = 0, p3 = 0;
        float* e = &st[r*65];   // reuse score tile as sort buffer
        for (int n = 0; n < 20; ++n) {
            const float v0 = lv[base      + p0];
            const float v1 = lv[base + 20 + p1];
            const float v2 = lv[base + 40 + p2];
            const float v3 = lv[base + 60 + p3];
            const int c0 = lc[base + p0], c1 = lc[base+20+p1];
            const int c2 = lc[base+40+p2], c3 = lc[base+60+p3];
            float bvv = v0; int bcc = c0; int bs = 0;
            if (v1 > bvv || (v1 == bvv && c1 < bcc)) { bvv=v1; bcc=c1; bs=1; }
            if (v2 > bvv || (v2 == bvv && c2 < bcc)) { bvv=v2; bcc=c2; bs=2; }
            if (v3 > bvv || (v3 == bvv && c3 < bcc)) { bvv=v3; bcc=c3; bs=3; }
            if (bs==0) ++p0; else if (bs==1) ++p1; else if (bs==2) ++p2; else ++p3;
            e[n] = errors[((size_t)(b*SS + bcc))*4];  // errors[..., 0]
        }
        for (int a = 1; a < 20; ++a) {     // insertion sort ascending
            const float v = e[a];
            int n = a;
            while (n > 0 && e[n-1] > v) { e[n] = e[n-1]; --n; }
            e[n] = v;
        }
        const float yp = y_pred[((size_t)(b*SS + sg))*4];
        const float yt = y[((size_t)(b*SS + sg))*4];
        float msum = 0.f;
        const size_t obase = ((size_t)(h*4 + b)*18)*2048 + sg;
        #pragma unroll 1
        for (int a = 0; a < 18; ++a) {
            const float alpha = c_alphas[a];
            const float beta  = 0.5f*alpha;
            const float pl = beta * 19.f;
            const int   il = (int)pl;
            const float fl = pl - (float)il;
            const float ql = e[il]*(1.f-fl) + e[il+1]*fl;
            const float qq = (1.f - alpha) + beta;
            const float ph = qq * 19.f;
            const int   ih = (int)ph;
            const float fh = ph - (float)ih;
            const float qh = e[ih]*(1.f-fh) + e[ih+1]*fh;
            msum += ql + qh;
            const size_t oidx = obase + (size_t)a*2048;
            out[OFF_YLOW  + oidx] = ql + yp;
            out[OFF_YHIGH + oidx] = qh + yp;
            out[OFF_QLOW  + oidx] = ql;
            out[OFF_QHIGH + oidx] = qh;
        }
        const float me = msum * (1.f/36.f);
        const float dd = yt - (me + yp);
        float sq = dd*dd;
        #pragma unroll
        for (int o = 32; o > 0; o >>= 1) sq += __shfl_xor(sq, o);
        if (r == 0) atomicAdd(&hacc[h], sq);
    }
}

__global__ void k_init(float* __restrict__ hacc) {
    if (threadIdx.x < 4) hacc[threadIdx.x] = 0.f;
}

__global__ __launch_bounds__(256) void k_finalize(
    const float* __restrict__ y, const float* __restrict__ y_pred,
    const float* __restrict__ errors, const float* __restrict__ hacc,
    float* __restrict__ out)
{
    const int i = blockIdx.x*256 + threadIdx.x;
    if (i == 0)
        out[0] = (hacc[0]+hacc[1]+hacc[2]+hacc[3]) * (1.f/32768.f);
    if (i < 32768)      out[OFF_Y + i] = y[i];
    else if (i < 65536) out[OFF_YPRED + (i - 32768)] = y_pred[i - 32768];
    else if (i < 73728) { const int j = i - 65536; out[OFF_ERR + j] = errors[(size_t)j*4]; }
}

extern "C" void kernel_launch(void* const* d_in, const int* in_sizes, int n_in,
                              void* d_out, int out_size, void* d_ws, size_t ws_size,
                              hipStream_t stream)
{
    const float* Xt     = (const float*)d_in[0];
    const float* Xs     = (const float*)d_in[1];
    const float* errors = (const float*)d_in[2];
    const float* y      = (const float*)d_in[3];
    const float* y_pred = (const float*)d_in[4];
    const float* W1 = (const float*)d_in[5];   const float* b1 = (const float*)d_in[6];
    const float* W2 = (const float*)d_in[7];   const float* b2 = (const float*)d_in[8];
    const float* W3 = (const float*)d_in[9];   const float* b3 = (const float*)d_in[10];
    const float* W4 = (const float*)d_in[11];  const float* b4 = (const float*)d_in[12];
    const float* Wq = (const float*)d_in[13];  const float* bq = (const float*)d_in[14];
    const float* Wk = (const float*)d_in[15];  const float* bk = (const float*)d_in[16];
    const float* g_q    = (const float*)d_in[17];
    const float* beta_q = (const float*)d_in[18];
    const float* g_k    = (const float*)d_in[19];
    const float* beta_k = (const float*)d_in[20];

    float* out  = (float*)d_out;
    float* ws   = (float*)d_ws;
    float* qbuf = ws;                 // 4,194,304 floats (16MB)
    float* kbuf = ws + 4194304;       // 16MB
    float* hacc = ws + 8388608;       // 4 floats

    k_init<<<1, 64, 0, stream>>>(hacc);
    k_mlp<<<1024, 256, 0, stream>>>(Xt, Xs, W1,b1,W2,b2,W3,b3,W4,b4,
                                    Wq,bq,Wk,bk,g_q,beta_q,g_k,beta_k,
                                    qbuf, kbuf);
    k_scores_topk<<<dim3(32,4,4), 256, 0, stream>>>(qbuf, kbuf, errors, y, y_pred, out, hacc);
    k_finalize<<<288, 256, 0, stream>>>(y, y_pred, errors, hacc, out);
}

// Round 3
// 1116.019 us; speedup vs baseline: 1.1159x; 1.1159x over previous
//
#include <hip/hip_runtime.h>
#include <hip/hip_bf16.h>
#include <math.h>

// ConformHopfieldBatch: B=4 S=2048 IN=64 D=128 HID=400 H=4 K=20 NQ=18
// softmax monotone -> top_k(assoc) == top_k(raw scores); softmax + 1/sqrt(D)
// skipped. Round-2 postmortem: ANY ~1e-4 score perturbation flips top-20 sets
// past tolerance -> selection must use fp32-exact scores. Strategy: bf16-hi
// MFMA PREFILTER (error ~0.013 << ~2.0 gap between global-rank-20 and
// per-slot-rank-20) builds 80 candidates/row; exact fp32 RESCORE of the 80
// candidates selects the true top-20 at fp32 noise (same regime as passing R1).
// R1 postmortem: per-lane lists must be lane-transposed (else 32-way bank
// conflicts burn 41% of CU cycles).

#define SS 2048

typedef short short8v __attribute__((ext_vector_type(8)));
typedef float float4v __attribute__((ext_vector_type(4)));

__constant__ float c_alphas[18] = {0.05f,0.06f,0.08f,0.1f,0.12f,0.14f,0.15f,0.17f,
                                   0.19f,0.2f,0.21f,0.23f,0.25f,0.3f,0.35f,0.38f,0.4f,0.45f};

// output flat offsets (return-order concat)
#define OFF_Y      1
#define OFF_YPRED  32769
#define OFF_YLOW   65537ll
#define OFF_YHIGH  655361ll
#define OFF_ERR    1245185ll
#define OFF_QLOW   1253377ll
#define OFF_QHIGH  1843201ll

__device__ inline short f2bf_s(float f) {
    __hip_bfloat16 h = __float2bfloat16(f);
    return __builtin_bit_cast(short, h);
}

// ---------------------------------------------------------------------------
// Kernel A: fused MLP(64->400->400->400->128) + LayerNorm + projection(128->512)
// 16 rows/block, 256 threads. blocks 0..511: true->q (fp32); 512..1023: sim->k
// (fp32 + bf16-hi). Head-major layout [(b*4+h)][s][128].
// ---------------------------------------------------------------------------
__global__ __launch_bounds__(256) void k_mlp(
    const float* __restrict__ Xt, const float* __restrict__ Xs,
    const float* __restrict__ W1, const float* __restrict__ b1,
    const float* __restrict__ W2, const float* __restrict__ b2,
    const float* __restrict__ W3, const float* __restrict__ b3,
    const float* __restrict__ W4, const float* __restrict__ b4,
    const float* __restrict__ Wq, const float* __restrict__ bq,
    const float* __restrict__ Wk, const float* __restrict__ bk,
    const float* __restrict__ g_q, const float* __restrict__ beta_q,
    const float* __restrict__ g_k, const float* __restrict__ beta_k,
    float* __restrict__ qf, float* __restrict__ kf,
    __hip_bfloat16* __restrict__ khi)
{
    __shared__ float xa[16*64];
    __shared__ float hA[16*400];
    __shared__ float hB[16*400];

    const int tid  = threadIdx.x;
    const int half = (blockIdx.x >= 512) ? 1 : 0;
    const int row0 = (blockIdx.x & 511) * 16;
    const float* X = half ? Xs : Xt;

    {
        const float4* src = (const float4*)(X + (size_t)row0 * 64);
        ((float4*)xa)[tid] = src[tid];
    }
    __syncthreads();

    // ---- layer 1: 64 -> 400 (relu) ----
    {
        const int j0 = tid, j1 = tid + 256;
        const bool v1 = (j1 < 400);
        const int j1m = v1 ? j1 : j0;
        float acc0[16], acc1[16];
        #pragma unroll
        for (int r = 0; r < 16; ++r) { acc0[r] = 0.f; acc1[r] = 0.f; }
        #pragma unroll 4
        for (int i = 0; i < 64; ++i) {
            const float w0 = W1[i*400 + j0];
            const float w1 = W1[i*400 + j1m];
            #pragma unroll
            for (int r = 0; r < 16; ++r) {
                const float x = xa[r*64 + i];
                acc0[r] = fmaf(x, w0, acc0[r]);
                acc1[r] = fmaf(x, w1, acc1[r]);
            }
        }
        const float bb0 = b1[j0], bb1 = b1[j1m];
        #pragma unroll
        for (int r = 0; r < 16; ++r) {
            hA[r*400 + j0] = fmaxf(acc0[r] + bb0, 0.f);
            if (v1) hA[r*400 + j1] = fmaxf(acc1[r] + bb1, 0.f);
        }
    }
    __syncthreads();

    // ---- layer 2: 400 -> 400 (relu) ----
    {
        const int j0 = tid, j1 = tid + 256;
        const bool v1 = (j1 < 400);
        const int j1m = v1 ? j1 : j0;
        float acc0[16], acc1[16];
        #pragma unroll
        for (int r = 0; r < 16; ++r) { acc0[r] = 0.f; acc1[r] = 0.f; }
        #pragma unroll 4
        for (int i = 0; i < 400; ++i) {
            const float w0 = W2[i*400 + j0];
            const float w1 = W2[i*400 + j1m];
            #pragma unroll
            for (int r = 0; r < 16; ++r) {
                const float x = hA[r*400 + i];
                acc0[r] = fmaf(x, w0, acc0[r]);
                acc1[r] = fmaf(x, w1, acc1[r]);
            }
        }
        const float bb0 = b2[j0], bb1 = b2[j1m];
        #pragma unroll
        for (int r = 0; r < 16; ++r) {
            hB[r*400 + j0] = fmaxf(acc0[r] + bb0, 0.f);
            if (v1) hB[r*400 + j1] = fmaxf(acc1[r] + bb1, 0.f);
        }
    }
    __syncthreads();

    // ---- layer 3: 400 -> 400 (relu) ----
    {
        const int j0 = tid, j1 = tid + 256;
        const bool v1 = (j1 < 400);
        const int j1m = v1 ? j1 : j0;
        float acc0[16], acc1[16];
        #pragma unroll
        for (int r = 0; r < 16; ++r) { acc0[r] = 0.f; acc1[r] = 0.f; }
        #pragma unroll 4
        for (int i = 0; i < 400; ++i) {
            const float w0 = W3[i*400 + j0];
            const float w1 = W3[i*400 + j1m];
            #pragma unroll
            for (int r = 0; r < 16; ++r) {
                const float x = hB[r*400 + i];
                acc0[r] = fmaf(x, w0, acc0[r]);
                acc1[r] = fmaf(x, w1, acc1[r]);
            }
        }
        const float bb0 = b3[j0], bb1 = b3[j1m];
        #pragma unroll
        for (int r = 0; r < 16; ++r) {
            hA[r*400 + j0] = fmaxf(acc0[r] + bb0, 0.f);
            if (v1) hA[r*400 + j1] = fmaxf(acc1[r] + bb1, 0.f);
        }
    }
    __syncthreads();

    // ---- layer 4: 400 -> 128 (no relu) ----
    {
        const int j  = tid & 127;
        const int r0 = (tid >> 7) * 8;
        float acc[8];
        #pragma unroll
        for (int r = 0; r < 8; ++r) acc[r] = 0.f;
        #pragma unroll 4
        for (int i = 0; i < 400; ++i) {
            const float w = W4[i*128 + j];
            #pragma unroll
            for (int r = 0; r < 8; ++r)
                acc[r] = fmaf(hA[(r0+r)*400 + i], w, acc[r]);
        }
        const float bb = b4[j];
        #pragma unroll
        for (int r = 0; r < 8; ++r)
            hB[(r0+r)*128 + j] = acc[r] + bb;
    }
    __syncthreads();

    // ---- LayerNorm -> hA (stride 128) ----
    {
        const float* g  = half ? g_k : g_q;
        const float* be = half ? beta_k : beta_q;
        const int lane = tid & 63;
        const int wg   = tid >> 6;
        const float gl0 = g[lane],  gl1 = g[lane+64];
        const float bl0 = be[lane], bl1 = be[lane+64];
        #pragma unroll 1
        for (int d = 0; d < 4; ++d) {
            const int r = wg*4 + d;
            const float v0 = hB[r*128 + lane];
            const float v1 = hB[r*128 + lane + 64];
            float s = v0 + v1;
            #pragma unroll
            for (int o = 32; o > 0; o >>= 1) s += __shfl_xor(s, o);
            const float mu = s * (1.f/128.f);
            const float d0 = v0 - mu, d1 = v1 - mu;
            float vs = d0*d0 + d1*d1;
            #pragma unroll
            for (int o = 32; o > 0; o >>= 1) vs += __shfl_xor(vs, o);
            const float rstd = rsqrtf(vs * (1.f/128.f) + 1e-5f);
            hA[r*128 + lane]      = d0*rstd*gl0 + bl0;
            hA[r*128 + lane + 64] = d1*rstd*gl1 + bl1;
        }
    }
    __syncthreads();

    // ---- projection 128 -> 512, fp32 write (+bf16-hi for k), head-major ----
    {
        const float* Wp = half ? Wk : Wq;
        const float* bp = half ? bk : bq;
        float* of = half ? kf : qf;
        const int j0 = tid, j1 = tid + 256;
        float acc0[16], acc1[16];
        #pragma unroll
        for (int r = 0; r < 16; ++r) { acc0[r] = 0.f; acc1[r] = 0.f; }
        #pragma unroll 4
        for (int i = 0; i < 128; ++i) {
            const float w0 = Wp[i*512 + j0];
            const float w1 = Wp[i*512 + j1];
            #pragma unroll
            for (int r = 0; r < 16; ++r) {
                const float x = hA[r*128 + i];
                acc0[r] = fmaf(x, w0, acc0[r]);
                acc1[r] = fmaf(x, w1, acc1[r]);
            }
        }
        const float bb0 = bp[j0], bb1 = bp[j1];
        const int h0 = j0 >> 7, d0 = j0 & 127;
        const int h1 = j1 >> 7, d1 = j1 & 127;
        #pragma unroll
        for (int r = 0; r < 16; ++r) {
            const int g  = row0 + r;
            const int bb = g >> 11, s = g & 2047;
            {
                const float v = acc0[r] + bb0;
                const size_t dst = ((size_t)(bb*4 + h0)*2048 + s)*128 + d0;
                of[dst] = v;
                if (half) khi[dst] = __float2bfloat16(v);
            }
            {
                const float v = acc1[r] + bb1;
                const size_t dst = ((size_t)(bb*4 + h1)*2048 + s)*128 + d1;
                of[dst] = v;
                if (half) khi[dst] = __float2bfloat16(v);
            }
        }
    }
}

// ---------------------------------------------------------------------------
// Kernel B: bf16-hi MFMA prefilter (80 candidates/row) + exact fp32 rescore +
// top-20 select + quantiles. Block = (stile,h,b): 64 q-rows x full m-range.
// MFMA layouts (m89/m91-verified): A[m=lane&15][k=quad*8+j],
// B[n=lane&15][k=quad*8+j], C: col=lane&15, row=quad*4+reg.
// Lists lane-transposed lv[n*256+tid] (conflict-free).
// ---------------------------------------------------------------------------
__global__ __launch_bounds__(256) void k_scores_topk(
    const float* __restrict__ qf, const float* __restrict__ kf,
    const __hip_bfloat16* __restrict__ khi,
    const float* __restrict__ errors, const float* __restrict__ y,
    const float* __restrict__ y_pred,
    float* __restrict__ out, float* __restrict__ hacc)
{
    __shared__ float st[64*65];            // 16640B score tile (stride 65)
    __shared__ float lv[20*256];           // 20480B list values  [n][tid]
    __shared__ unsigned short lc[20*256];  // 10240B list cols    [n][tid]

    const int tid   = threadIdx.x;
    const int stile = blockIdx.x;   // 0..31
    const int h     = blockIdx.y;
    const int b     = blockIdx.z;

    #pragma unroll
    for (int n = 0; n < 20; ++n) { lv[n*256 + tid] = -INFINITY; lc[n*256 + tid] = 0; }

    const int lane = tid & 63;
    const int w    = tid >> 6;
    const int m16  = lane & 15;
    const int quad = lane >> 4;

    const size_t slab = (size_t)(b*4 + h) * 2048;

    // build persistent Q fragments (bf16-hi of fp32 q) for rows stile*64+w*16..+15
    short8v aq[4];
    {
        const int qrow = stile*64 + w*16 + m16;
        const float* qp = qf + (slab + qrow)*128 + quad*8;
        #pragma unroll
        for (int ks = 0; ks < 4; ++ks) {
            const float4 x0 = *(const float4*)(qp + ks*32);
            const float4 x1 = *(const float4*)(qp + ks*32 + 4);
            short8v t;
            t[0]=f2bf_s(x0.x); t[1]=f2bf_s(x0.y); t[2]=f2bf_s(x0.z); t[3]=f2bf_s(x0.w);
            t[4]=f2bf_s(x1.x); t[5]=f2bf_s(x1.y); t[6]=f2bf_s(x1.z); t[7]=f2bf_s(x1.w);
            aq[ks] = t;
        }
    }

    const int myr   = lane;      // scan row
    const int slot  = w;         // scan col-slot
    float lmin = -INFINITY;
    const int sg_my = stile*64 + myr;

    for (int mt = 0; mt < 32; ++mt) {
        float4v acc[4];
        #pragma unroll
        for (int ct = 0; ct < 4; ++ct) acc[ct] = (float4v){0.f,0.f,0.f,0.f};

        #pragma unroll 1
        for (int ct = 0; ct < 4; ++ct) {
            const int col = mt*64 + ct*16 + m16;
            const __hip_bfloat16* kp = khi + (slab + col)*128 + quad*8;
            #pragma unroll
            for (int ks = 0; ks < 4; ++ks) {
                const short8v bh = *(const short8v*)(kp + ks*32);
                acc[ct] = __builtin_amdgcn_mfma_f32_16x16x32_bf16(aq[ks], bh, acc[ct], 0, 0, 0);
            }
        }

        __syncthreads();   // previous scan done reading st
        #pragma unroll
        for (int ct = 0; ct < 4; ++ct)
            #pragma unroll
            for (int reg = 0; reg < 4; ++reg)
                st[(w*16 + quad*4 + reg)*65 + ct*16 + m16] = acc[ct][reg];
        __syncthreads();

        // streaming approx top-20 per (row, slot)
        const int mbase = mt*64;
        for (int jj = 0; jj < 16; ++jj) {
            const int c = slot*16 + jj;
            const int m = mbase + c;
            const float v = st[myr*65 + c];
            if (m != sg_my && v > lmin) {          // skip diagonal
                int n = 19;
                while (n > 0 && lv[(n-1)*256 + tid] < v) {
                    lv[n*256 + tid] = lv[(n-1)*256 + tid];
                    lc[n*256 + tid] = lc[(n-1)*256 + tid];
                    --n;
                }
                lv[n*256 + tid] = v;
                lc[n*256 + tid] = (unsigned short)m;
                lmin = lv[19*256 + tid];
            }
        }
    }
    __syncthreads();

    // ---- Phase 1: exact fp32 rescore of this thread's 20 candidates ----
    {
        const float* qrow_p = qf + (slab + (size_t)sg_my)*128;
        #pragma unroll 1
        for (int n = 0; n < 20; ++n) {
            const int col = lc[n*256 + tid];
            const float* kcol = kf + (slab + (size_t)col)*128;
            float s0 = 0.f, s1 = 0.f, s2 = 0.f, s3 = 0.f;
            #pragma unroll 8
            for (int i = 0; i < 32; ++i) {
                const float4 qv = *(const float4*)(qrow_p + i*4);
                const float4 kv = *(const float4*)(kcol + i*4);
                s0 = fmaf(qv.x, kv.x, s0);
                s1 = fmaf(qv.y, kv.y, s1);
                s2 = fmaf(qv.z, kv.z, s2);
                s3 = fmaf(qv.w, kv.w, s3);
            }
            lv[n*256 + tid] = (s0 + s1) + (s2 + s3);
        }
    }

    // ---- Phase 2: per-thread insertion sort (exact desc, col asc on ties) ----
    {
        for (int a = 1; a < 20; ++a) {
            const float v = lv[a*256 + tid];
            const unsigned short c = lc[a*256 + tid];
            int n = a;
            while (n > 0) {
                const float pv = lv[(n-1)*256 + tid];
                const unsigned short pc = lc[(n-1)*256 + tid];
                if (pv > v || (pv == v && pc < c)) break;
                lv[n*256 + tid] = pv;
                lc[n*256 + tid] = pc;
                --n;
            }
            lv[n*256 + tid] = v;
            lc[n*256 + tid] = c;
        }
    }
    __syncthreads();

    // ---- Phase 3: wave0 merges 4 sorted lists -> true top-20 -> quantiles ----
    if (tid < 64) {
        const int r  = tid;
        const int sg = stile*64 + r;
        int p0 = 0, p1 = 0, p2 = 0, p3 = 0;
        float* e = &st[r*65];   // reuse score tile as sort buffer
        for (int n = 0; n < 20; ++n) {
            const float v0 = lv[p0*256 +       r];
            const float v1 = lv[p1*256 +  64 + r];
            const float v2 = lv[p2*256 + 128 + r];
            const float v3 = lv[p3*256 + 192 + r];
            const int c0 = lc[p0*256 +       r], c1 = lc[p1*256 +  64 + r];
            const int c2 = lc[p2*256 + 128 + r], c3 = lc[p3*256 + 192 + r];
            float bvv = v0; int bcc = c0; int bs = 0;
            if (v1 > bvv || (v1 == bvv && c1 < bcc)) { bvv=v1; bcc=c1; bs=1; }
            if (v2 > bvv || (v2 == bvv && c2 < bcc)) { bvv=v2; bcc=c2; bs=2; }
            if (v3 > bvv || (v3 == bvv && c3 < bcc)) { bvv=v3; bcc=c3; bs=3; }
            if (bs==0) ++p0; else if (bs==1) ++p1; else if (bs==2) ++p2; else ++p3;
            e[n] = errors[((size_t)(b*SS + bcc))*4];  // errors[..., 0]
        }
        for (int a = 1; a < 20; ++a) {     // insertion sort ascending
            const float v = e[a];
            int n = a;
            while (n > 0 && e[n-1] > v) { e[n] = e[n-1]; --n; }
            e[n] = v;
        }
        const float yp = y_pred[((size_t)(b*SS + sg))*4];
        const float yt = y[((size_t)(b*SS + sg))*4];
        float msum = 0.f;
        const size_t obase = ((size_t)(h*4 + b)*18)*2048 + sg;
        #pragma unroll 1
        for (int a = 0; a < 18; ++a) {
            const float alpha = c_alphas[a];
            const float beta  = 0.5f*alpha;
            const float pl = beta * 19.f;
            const int   il = (int)pl;
            const float fl = pl - (float)il;
            const float ql = e[il]*(1.f-fl) + e[il+1]*fl;
            const float qq = (1.f - alpha) + beta;
            const float ph = qq * 19.f;
            const int   ih = (int)ph;
            const float fh = ph - (float)ih;
            const float qh = e[ih]*(1.f-fh) + e[ih+1]*fh;
            msum += ql + qh;
            const size_t oidx = obase + (size_t)a*2048;
            out[OFF_YLOW  + oidx] = ql + yp;
            out[OFF_YHIGH + oidx] = qh + yp;
            out[OFF_QLOW  + oidx] = ql;
            out[OFF_QHIGH + oidx] = qh;
        }
        const float me = msum * (1.f/36.f);
        const float dd = yt - (me + yp);
        float sq = dd*dd;
        #pragma unroll
        for (int o = 32; o > 0; o >>= 1) sq += __shfl_xor(sq, o);
        if (r == 0) atomicAdd(&hacc[h], sq);
    }
}

__global__ void k_init(float* __restrict__ hacc) {
    if (threadIdx.x < 4) hacc[threadIdx.x] = 0.f;
}

__global__ __launch_bounds__(256) void k_finalize(
    const float* __restrict__ y, const float* __restrict__ y_pred,
    const float* __restrict__ errors, const float* __restrict__ hacc,
    float* __restrict__ out)
{
    const int i = blockIdx.x*256 + threadIdx.x;
    if (i == 0)
        out[0] = (hacc[0]+hacc[1]+hacc[2]+hacc[3]) * (1.f/32768.f);
    if (i < 32768)      out[OFF_Y + i] = y[i];
    else if (i < 65536) out[OFF_YPRED + (i - 32768)] = y_pred[i - 32768];
    else if (i < 73728) { const int j = i - 65536; out[OFF_ERR + j] = errors[(size_t)j*4]; }
}

extern "C" void kernel_launch(void* const* d_in, const int* in_sizes, int n_in,
                              void* d_out, int out_size, void* d_ws, size_t ws_size,
                              hipStream_t stream)
{
    const float* Xt     = (const float*)d_in[0];
    const float* Xs     = (const float*)d_in[1];
    const float* errors = (const float*)d_in[2];
    const float* y      = (const float*)d_in[3];
    const float* y_pred = (const float*)d_in[4];
    const float* W1 = (const float*)d_in[5];   const float* b1 = (const float*)d_in[6];
    const float* W2 = (const float*)d_in[7];   const float* b2 = (const float*)d_in[8];
    const float* W3 = (const float*)d_in[9];   const float* b3 = (const float*)d_in[10];
    const float* W4 = (const float*)d_in[11];  const float* b4 = (const float*)d_in[12];
    const float* Wq = (const float*)d_in[13];  const float* bq = (const float*)d_in[14];
    const float* Wk = (const float*)d_in[15];  const float* bk = (const float*)d_in[16];
    const float* g_q    = (const float*)d_in[17];
    const float* beta_q = (const float*)d_in[18];
    const float* g_k    = (const float*)d_in[19];
    const float* beta_k = (const float*)d_in[20];

    float* out  = (float*)d_out;
    float* hacc = (float*)d_ws;
    const size_t SLAB = (size_t)16*2048*128;   // 4,194,304 elements
    float* qf = (float*)d_ws + 16;             // 16MB
    float* kf = qf + SLAB;                     // 16MB
    __hip_bfloat16* khi = (__hip_bfloat16*)(kf + SLAB);  // 8MB

    k_init<<<1, 64, 0, stream>>>(hacc);
    k_mlp<<<1024, 256, 0, stream>>>(Xt, Xs, W1,b1,W2,b2,W3,b3,W4,b4,
                                    Wq,bq,Wk,bk,g_q,beta_q,g_k,beta_k,
                                    qf, kf, khi);
    k_scores_topk<<<dim3(32,4,4), 256, 0, stream>>>(qf, kf, khi,
                                                    errors, y, y_pred, out, hacc);
    k_finalize<<<288, 256, 0, stream>>>(y, y_pred, errors, hacc, out);
}

// Round 4
// 892.525 us; speedup vs baseline: 1.3953x; 1.2504x over previous
//
#include <hip/hip_runtime.h>
#include <hip/hip_bf16.h>
#include <math.h>

// ConformHopfieldBatch: B=4 S=2048 IN=64 D=128 HID=400 H=4 K=20 NQ=18
// softmax monotone -> top_k(assoc) == top_k(raw scores). bf16-hi MFMA
// PREFILTER (err ~0.013 + key-quant ~4e-3 << ~2.0 slot margin) -> 80
// candidates/row; exact fp32 RESCORE selects true top-20 (R2 lesson: selection
// needs fp32-exact scores). R3 postmortem: divergent LDS insert loop burned
// ~95% of k_scores_topk -> top-20 now BRANCHLESS in registers (packed u32
// keys, 19 cmp-swap bubble). K-loop software-pipelined: dbuf score tile
// (1 barrier/mt) + register prefetch of next K-frags. k_mlp: broadcast LDS
// reads float4-ized (same FMA order -> bit-identical enc).

#define SS 2048

typedef short short8v __attribute__((ext_vector_type(8)));
typedef float float4v __attribute__((ext_vector_type(4)));

__constant__ float c_alphas[18] = {0.05f,0.06f,0.08f,0.1f,0.12f,0.14f,0.15f,0.17f,
                                   0.19f,0.2f,0.21f,0.23f,0.25f,0.3f,0.35f,0.38f,0.4f,0.45f};

// output flat offsets (return-order concat)
#define OFF_Y      1
#define OFF_YPRED  32769
#define OFF_YLOW   65537ll
#define OFF_YHIGH  655361ll
#define OFF_ERR    1245185ll
#define OFF_QLOW   1253377ll
#define OFF_QHIGH  1843201ll

__device__ inline short f2bf_s(float f) {
    __hip_bfloat16 h = __float2bfloat16(f);
    return __builtin_bit_cast(short, h);
}
// monotone fp32 -> u32 map (order-preserving)
__device__ inline unsigned mono(float f) {
    unsigned u = __builtin_bit_cast(unsigned, f);
    return (u & 0x80000000u) ? ~u : (u | 0x80000000u);
}

// ---------------------------------------------------------------------------
// Kernel A: fused MLP(64->400->400->400->128) + LayerNorm + projection(128->512)
// 16 rows/block, 256 threads. blocks 0..511: true->q (fp32); 512..1023: sim->k
// (fp32 + bf16-hi). Head-major layout [(b*4+h)][s][128].
// Activation reads are broadcast (same addr all lanes) -> float4-ized, FMA
// order over i preserved exactly (bit-identical to scalar version).
// ---------------------------------------------------------------------------
__global__ __launch_bounds__(256) void k_mlp(
    const float* __restrict__ Xt, const float* __restrict__ Xs,
    const float* __restrict__ W1, const float* __restrict__ b1,
    const float* __restrict__ W2, const float* __restrict__ b2,
    const float* __restrict__ W3, const float* __restrict__ b3,
    const float* __restrict__ W4, const float* __restrict__ b4,
    const float* __restrict__ Wq, const float* __restrict__ bq,
    const float* __restrict__ Wk, const float* __restrict__ bk,
    const float* __restrict__ g_q, const float* __restrict__ beta_q,
    const float* __restrict__ g_k, const float* __restrict__ beta_k,
    float* __restrict__ qf, float* __restrict__ kf,
    __hip_bfloat16* __restrict__ khi)
{
    __shared__ float xa[16*64];
    __shared__ float hA[16*400];
    __shared__ float hB[16*400];

    const int tid  = threadIdx.x;
    const int half = (blockIdx.x >= 512) ? 1 : 0;
    const int row0 = (blockIdx.x & 511) * 16;
    const float* X = half ? Xs : Xt;

    {
        const float4* src = (const float4*)(X + (size_t)row0 * 64);
        ((float4*)xa)[tid] = src[tid];
    }
    __syncthreads();

    // ---- layer 1: 64 -> 400 (relu) ----
    {
        const int j0 = tid, j1 = tid + 256;
        const bool v1 = (j1 < 400);
        const int j1m = v1 ? j1 : j0;
        float acc0[16], acc1[16];
        #pragma unroll
        for (int r = 0; r < 16; ++r) { acc0[r] = 0.f; acc1[r] = 0.f; }
        #pragma unroll 2
        for (int i = 0; i < 64; i += 4) {
            float w0a[4], w1a[4];
            #pragma unroll
            for (int u = 0; u < 4; ++u) { w0a[u] = W1[(i+u)*400 + j0]; w1a[u] = W1[(i+u)*400 + j1m]; }
            #pragma unroll
            for (int r = 0; r < 16; ++r) {
                const float4 xv = *(const float4*)&xa[r*64 + i];
                acc0[r] = fmaf(xv.x, w0a[0], acc0[r]); acc1[r] = fmaf(xv.x, w1a[0], acc1[r]);
                acc0[r] = fmaf(xv.y, w0a[1], acc0[r]); acc1[r] = fmaf(xv.y, w1a[1], acc1[r]);
                acc0[r] = fmaf(xv.z, w0a[2], acc0[r]); acc1[r] = fmaf(xv.z, w1a[2], acc1[r]);
                acc0[r] = fmaf(xv.w, w0a[3], acc0[r]); acc1[r] = fmaf(xv.w, w1a[3], acc1[r]);
            }
        }
        const float bb0 = b1[j0], bb1 = b1[j1m];
        #pragma unroll
        for (int r = 0; r < 16; ++r) {
            hA[r*400 + j0] = fmaxf(acc0[r] + bb0, 0.f);
            if (v1) hA[r*400 + j1] = fmaxf(acc1[r] + bb1, 0.f);
        }
    }
    __syncthreads();

    // ---- layer 2: 400 -> 400 (relu), hA -> hB ----
    {
        const int j0 = tid, j1 = tid + 256;
        const bool v1 = (j1 < 400);
        const int j1m = v1 ? j1 : j0;
        float acc0[16], acc1[16];
        #pragma unroll
        for (int r = 0; r < 16; ++r) { acc0[r] = 0.f; acc1[r] = 0.f; }
        #pragma unroll 2
        for (int i = 0; i < 400; i += 4) {
            float w0a[4], w1a[4];
            #pragma unroll
            for (int u = 0; u < 4; ++u) { w0a[u] = W2[(i+u)*400 + j0]; w1a[u] = W2[(i+u)*400 + j1m]; }
            #pragma unroll
            for (int r = 0; r < 16; ++r) {
                const float4 xv = *(const float4*)&hA[r*400 + i];
                acc0[r] = fmaf(xv.x, w0a[0], acc0[r]); acc1[r] = fmaf(xv.x, w1a[0], acc1[r]);
                acc0[r] = fmaf(xv.y, w0a[1], acc0[r]); acc1[r] = fmaf(xv.y, w1a[1], acc1[r]);
                acc0[r] = fmaf(xv.z, w0a[2], acc0[r]); acc1[r] = fmaf(xv.z, w1a[2], acc1[r]);
                acc0[r] = fmaf(xv.w, w0a[3], acc0[r]); acc1[r] = fmaf(xv.w, w1a[3], acc1[r]);
            }
        }
        const float bb0 = b2[j0], bb1 = b2[j1m];
        #pragma unroll
        for (int r = 0; r < 16; ++r) {
            hB[r*400 + j0] = fmaxf(acc0[r] + bb0, 0.f);
            if (v1) hB[r*400 + j1] = fmaxf(acc1[r] + bb1, 0.f);
        }
    }
    __syncthreads();

    // ---- layer 3: 400 -> 400 (relu), hB -> hA ----
    {
        const int j0 = tid, j1 = tid + 256;
        const bool v1 = (j1 < 400);
        const int j1m = v1 ? j1 : j0;
        float acc0[16], acc1[16];
        #pragma unroll
        for (int r = 0; r < 16; ++r) { acc0[r] = 0.f; acc1[r] = 0.f; }
        #pragma unroll 2
        for (int i = 0; i < 400; i += 4) {
            float w0a[4], w1a[4];
            #pragma unroll
            for (int u = 0; u < 4; ++u) { w0a[u] = W3[(i+u)*400 + j0]; w1a[u] = W3[(i+u)*400 + j1m]; }
            #pragma unroll
            for (int r = 0; r < 16; ++r) {
                const float4 xv = *(const float4*)&hB[r*400 + i];
                acc0[r] = fmaf(xv.x, w0a[0], acc0[r]); acc1[r] = fmaf(xv.x, w1a[0], acc1[r]);
                acc0[r] = fmaf(xv.y, w0a[1], acc0[r]); acc1[r] = fmaf(xv.y, w1a[1], acc1[r]);
                acc0[r] = fmaf(xv.z, w0a[2], acc0[r]); acc1[r] = fmaf(xv.z, w1a[2], acc1[r]);
                acc0[r] = fmaf(xv.w, w0a[3], acc0[r]); acc1[r] = fmaf(xv.w, w1a[3], acc1[r]);
            }
        }
        const float bb0 = b3[j0], bb1 = b3[j1m];
        #pragma unroll
        for (int r = 0; r < 16; ++r) {
            hA[r*400 + j0] = fmaxf(acc0[r] + bb0, 0.f);
            if (v1) hA[r*400 + j1] = fmaxf(acc1[r] + bb1, 0.f);
        }
    }
    __syncthreads();

    // ---- layer 4: 400 -> 128 (no relu), hA -> hB (stride 128) ----
    {
        const int j  = tid & 127;
        const int r0 = (tid >> 7) * 8;
        float acc[8];
        #pragma unroll
        for (int r = 0; r < 8; ++r) acc[r] = 0.f;
        #pragma unroll 2
        for (int i = 0; i < 400; i += 4) {
            float wa[4];
            #pragma unroll
            for (int u = 0; u < 4; ++u) wa[u] = W4[(i+u)*128 + j];
            #pragma unroll
            for (int r = 0; r < 8; ++r) {
                const float4 xv = *(const float4*)&hA[(r0+r)*400 + i];
                acc[r] = fmaf(xv.x, wa[0], acc[r]);
                acc[r] = fmaf(xv.y, wa[1], acc[r]);
                acc[r] = fmaf(xv.z, wa[2], acc[r]);
                acc[r] = fmaf(xv.w, wa[3], acc[r]);
            }
        }
        const float bb = b4[j];
        #pragma unroll
        for (int r = 0; r < 8; ++r)
            hB[(r0+r)*128 + j] = acc[r] + bb;
    }
    __syncthreads();

    // ---- LayerNorm -> hA (stride 128) ----
    {
        const float* g  = half ? g_k : g_q;
        const float* be = half ? beta_k : beta_q;
        const int lane = tid & 63;
        const int wg   = tid >> 6;
        const float gl0 = g[lane],  gl1 = g[lane+64];
        const float bl0 = be[lane], bl1 = be[lane+64];
        #pragma unroll 1
        for (int d = 0; d < 4; ++d) {
            const int r = wg*4 + d;
            const float v0 = hB[r*128 + lane];
            const float v1 = hB[r*128 + lane + 64];
            float s = v0 + v1;
            #pragma unroll
            for (int o = 32; o > 0; o >>= 1) s += __shfl_xor(s, o);
            const float mu = s * (1.f/128.f);
            const float d0 = v0 - mu, d1 = v1 - mu;
            float vs = d0*d0 + d1*d1;
            #pragma unroll
            for (int o = 32; o > 0; o >>= 1) vs += __shfl_xor(vs, o);
            const float rstd = rsqrtf(vs * (1.f/128.f) + 1e-5f);
            hA[r*128 + lane]      = d0*rstd*gl0 + bl0;
            hA[r*128 + lane + 64] = d1*rstd*gl1 + bl1;
        }
    }
    __syncthreads();

    // ---- projection 128 -> 512, fp32 write (+bf16-hi for k), head-major ----
    {
        const float* Wp = half ? Wk : Wq;
        const float* bp = half ? bk : bq;
        float* of = half ? kf : qf;
        const int j0 = tid, j1 = tid + 256;
        float acc0[16], acc1[16];
        #pragma unroll
        for (int r = 0; r < 16; ++r) { acc0[r] = 0.f; acc1[r] = 0.f; }
        #pragma unroll 2
        for (int i = 0; i < 128; i += 4) {
            float w0a[4], w1a[4];
            #pragma unroll
            for (int u = 0; u < 4; ++u) { w0a[u] = Wp[(i+u)*512 + j0]; w1a[u] = Wp[(i+u)*512 + j1]; }
            #pragma unroll
            for (int r = 0; r < 16; ++r) {
                const float4 xv = *(const float4*)&hA[r*128 + i];
                acc0[r] = fmaf(xv.x, w0a[0], acc0[r]); acc1[r] = fmaf(xv.x, w1a[0], acc1[r]);
                acc0[r] = fmaf(xv.y, w0a[1], acc0[r]); acc1[r] = fmaf(xv.y, w1a[1], acc1[r]);
                acc0[r] = fmaf(xv.z, w0a[2], acc0[r]); acc1[r] = fmaf(xv.z, w1a[2], acc1[r]);
                acc0[r] = fmaf(xv.w, w0a[3], acc0[r]); acc1[r] = fmaf(xv.w, w1a[3], acc1[r]);
            }
        }
        const float bb0 = bp[j0], bb1 = bp[j1];
        const int h0 = j0 >> 7, d0 = j0 & 127;
        const int h1 = j1 >> 7, d1 = j1 & 127;
        #pragma unroll
        for (int r = 0; r < 16; ++r) {
            const int g  = row0 + r;
            const int bb = g >> 11, s = g & 2047;
            {
                const float v = acc0[r] + bb0;
                const size_t dst = ((size_t)(bb*4 + h0)*2048 + s)*128 + d0;
                of[dst] = v;
                if (half) khi[dst] = __float2bfloat16(v);
            }
            {
                const float v = acc1[r] + bb1;
                const size_t dst = ((size_t)(bb*4 + h1)*2048 + s)*128 + d1;
                of[dst] = v;
                if (half) khi[dst] = __float2bfloat16(v);
            }
        }
    }
}

// ---------------------------------------------------------------------------
// Kernel B: bf16-hi MFMA prefilter + branchless register top-20 + exact fp32
// rescore + merge + quantiles. Block = (stile,h,b): 64 q-rows x full m-range.
// Pipelined: register-prefetch next K-frags, double-buffered score tile,
// ONE barrier per mt. Keys: (mono(score) & ~0x7FF) | col  -- 21 score bits
// (granularity ~4e-3 << ~2.0 slot margin), 11 col bits.
// MFMA layouts (m89/m91-verified): A[m=lane&15][k=quad*8+j],
// B[n=lane&15][k=quad*8+j], C: col=lane&15, row=quad*4+reg.
// ---------------------------------------------------------------------------
__global__ __launch_bounds__(256) void k_scores_topk(
    const float* __restrict__ qf, const float* __restrict__ kf,
    const __hip_bfloat16* __restrict__ khi,
    const float* __restrict__ errors, const float* __restrict__ y,
    const float* __restrict__ y_pred,
    float* __restrict__ out, float* __restrict__ hacc)
{
    __shared__ float st[2][64*65];         // 2x16640B dbuf score tile (stride 65)
    __shared__ float lv[20*256];           // 20480B exact scores [n][tid]
    __shared__ unsigned short lc[20*256];  // 10240B cols         [n][tid]

    const int tid   = threadIdx.x;
    const int stile = blockIdx.x;   // 0..31
    const int h     = blockIdx.y;
    const int b     = blockIdx.z;

    const int lane = tid & 63;
    const int w    = tid >> 6;
    const int m16  = lane & 15;
    const int quad = lane >> 4;

    const size_t slab  = (size_t)(b*4 + h) * 2048;
    const __hip_bfloat16* slabp = khi + slab*128;

    // persistent Q fragments (bf16-hi of fp32 q) for rows stile*64 + w*16..+15
    short8v aq[4];
    {
        const int qrow = stile*64 + w*16 + m16;
        const float* qp = qf + (slab + qrow)*128 + quad*8;
        #pragma unroll
        for (int ks = 0; ks < 4; ++ks) {
            const float4 x0 = *(const float4*)(qp + ks*32);
            const float4 x1 = *(const float4*)(qp + ks*32 + 4);
            short8v t;
            t[0]=f2bf_s(x0.x); t[1]=f2bf_s(x0.y); t[2]=f2bf_s(x0.z); t[3]=f2bf_s(x0.w);
            t[4]=f2bf_s(x1.x); t[5]=f2bf_s(x1.y); t[6]=f2bf_s(x1.z); t[7]=f2bf_s(x1.w);
            aq[ks] = t;
        }
    }

    const int myr   = lane;      // scan row
    const int slot  = w;         // scan col-slot
    const int sg_my = stile*64 + myr;

    // register-resident top-20 keys (ascending; keys[0] = current min)
    unsigned keys[20];
    #pragma unroll
    for (int n = 0; n < 20; ++n) keys[n] = 0u;

    // K-fragment prefetch buffers
    short8v kra[16], krb[16];
    {   // preload tile 0
        #pragma unroll
        for (int ct = 0; ct < 4; ++ct) {
            const __hip_bfloat16* kp = slabp + (size_t)(ct*16 + m16)*128 + quad*8;
            #pragma unroll
            for (int ks = 0; ks < 4; ++ks)
                kra[ct*4+ks] = *(const short8v*)(kp + ks*32);
        }
    }

    for (int mt = 0; mt < 32; ++mt) {
        short8v* cur = (mt & 1) ? krb : kra;
        short8v* nxt = (mt & 1) ? kra : krb;
        const int p = mt & 1;

        // issue prefetch for mt+1 (hidden under MFMA + barrier + scan)
        if (mt < 31) {
            const int colb = (mt+1)*64 + m16;
            #pragma unroll
            for (int ct = 0; ct < 4; ++ct) {
                const __hip_bfloat16* kp = slabp + (size_t)(colb + ct*16)*128 + quad*8;
                #pragma unroll
                for (int ks = 0; ks < 4; ++ks)
                    nxt[ct*4+ks] = *(const short8v*)(kp + ks*32);
            }
        }

        // MFMA tile from prefetched regs
        float4v acc[4];
        #pragma unroll
        for (int ct = 0; ct < 4; ++ct) {
            acc[ct] = (float4v){0.f,0.f,0.f,0.f};
            #pragma unroll
            for (int ks = 0; ks < 4; ++ks)
                acc[ct] = __builtin_amdgcn_mfma_f32_16x16x32_bf16(aq[ks], cur[ct*4+ks], acc[ct], 0, 0, 0);
        }
        #pragma unroll
        for (int ct = 0; ct < 4; ++ct)
            #pragma unroll
            for (int reg = 0; reg < 4; ++reg)
                st[p][(w*16 + quad*4 + reg)*65 + ct*16 + m16] = acc[ct][reg];
        __syncthreads();   // writes visible; also fences scan(mt-1) vs write(mt+1)

        // branchless top-20 key insert (zero divergence, zero LDS traffic)
        const int mbase = mt*64;
        const float* strow = &st[p][myr*65 + slot*16];
        #pragma unroll 4
        for (int jj = 0; jj < 16; ++jj) {
            const int m = mbase + slot*16 + jj;
            const float v = strow[jj];
            unsigned key = (mono(v) & 0xFFFFF800u) | (unsigned)m;
            key = (m == sg_my) ? 0u : key;           // diagonal excluded
            keys[0] = (key > keys[0]) ? key : keys[0];  // drop-min insert
            #pragma unroll
            for (int i = 0; i < 19; ++i) {           // one bubble pass restores order
                const unsigned a = keys[i], c = keys[i+1];
                keys[i]   = (a < c) ? a : c;
                keys[i+1] = (a < c) ? c : a;
            }
        }
    }

    // ---- exact fp32 rescore of this thread's 20 candidates ----
    {
        const float* qrow_p = qf + (slab + (size_t)sg_my)*128;
        #pragma unroll 1
        for (int n = 0; n < 20; ++n) {
            const int col = (int)(keys[n] & 0x7FFu);
            const float* kcol = kf + (slab + (size_t)col)*128;
            float s0 = 0.f, s1 = 0.f, s2 = 0.f, s3 = 0.f;
            #pragma unroll 8
            for (int i = 0; i < 32; ++i) {
                const float4 qv = *(const float4*)(qrow_p + i*4);
                const float4 kv = *(const float4*)(kcol + i*4);
                s0 = fmaf(qv.x, kv.x, s0);
                s1 = fmaf(qv.y, kv.y, s1);
                s2 = fmaf(qv.z, kv.z, s2);
                s3 = fmaf(qv.w, kv.w, s3);
            }
            lv[n*256 + tid] = (s0 + s1) + (s2 + s3);
            lc[n*256 + tid] = (unsigned short)col;
        }
    }

    // ---- per-thread insertion sort (exact desc, col asc on ties) ----
    {
        for (int a = 1; a < 20; ++a) {
            const float v = lv[a*256 + tid];
            const unsigned short c = lc[a*256 + tid];
            int n = a;
            while (n > 0) {
                const float pv = lv[(n-1)*256 + tid];
                const unsigned short pc = lc[(n-1)*256 + tid];
                if (pv > v || (pv == v && pc < c)) break;
                lv[n*256 + tid] = pv;
                lc[n*256 + tid] = pc;
                --n;
            }
            lv[n*256 + tid] = v;
            lc[n*256 + tid] = c;
        }
    }
    __syncthreads();

    // ---- wave0 merges 4 sorted lists -> true top-20 -> quantiles ----
    if (tid < 64) {
        const int r  = tid;
        const int sg = stile*64 + r;
        int p0 = 0, p1 = 0, p2 = 0, p3 = 0;
        float* e = &st[0][r*65];   // reuse score tile as sort buffer
        for (int n = 0; n < 20; ++n) {
            const float v0 = lv[p0*256 +       r];
            const float v1 = lv[p1*256 +  64 + r];
            const float v2 = lv[p2*256 + 128 + r];
            const float v3 = lv[p3*256 + 192 + r];
            const int c0 = lc[p0*256 +       r], c1 = lc[p1*256 +  64 + r];
            const int c2 = lc[p2*256 + 128 + r], c3 = lc[p3*256 + 192 + r];
            float bvv = v0; int bcc = c0; int bs = 0;
            if (v1 > bvv || (v1 == bvv && c1 < bcc)) { bvv=v1; bcc=c1; bs=1; }
            if (v2 > bvv || (v2 == bvv && c2 < bcc)) { bvv=v2; bcc=c2; bs=2; }
            if (v3 > bvv || (v3 == bvv && c3 < bcc)) { bvv=v3; bcc=c3; bs=3; }
            if (bs==0) ++p0; else if (bs==1) ++p1; else if (bs==2) ++p2; else ++p3;
            e[n] = errors[((size_t)(b*SS + bcc))*4];  // errors[..., 0]
        }
        for (int a = 1; a < 20; ++a) {     // insertion sort ascending
            const float v = e[a];
            int n = a;
            while (n > 0 && e[n-1] > v) { e[n] = e[n-1]; --n; }
            e[n] = v;
        }
        const float yp = y_pred[((size_t)(b*SS + sg))*4];
        const float yt = y[((size_t)(b*SS + sg))*4];
        float msum = 0.f;
        const size_t obase = ((size_t)(h*4 + b)*18)*2048 + sg;
        #pragma unroll 1
        for (int a = 0; a < 18; ++a) {
            const float alpha = c_alphas[a];
            const float beta  = 0.5f*alpha;
            const float pl = beta * 19.f;
            const int   il = (int)pl;
            const float fl = pl - (float)il;
            const float ql = e[il]*(1.f-fl) + e[il+1]*fl;
            const float qq = (1.f - alpha) + beta;
            const float ph = qq * 19.f;
            const int   ih = (int)ph;
            const float fh = ph - (float)ih;
            const float qh = e[ih]*(1.f-fh) + e[ih+1]*fh;
            msum += ql + qh;
            const size_t oidx = obase + (size_t)a*2048;
            out[OFF_YLOW  + oidx] = ql + yp;
            out[OFF_YHIGH + oidx] = qh + yp;
            out[OFF_QLOW  + oidx] = ql;
            out[OFF_QHIGH + oidx] = qh;
        }
        const float me = msum * (1.f/36.f);
        const float dd = yt - (me + yp);
        float sq = dd*dd;
        #pragma unroll
        for (int o = 32; o > 0; o >>= 1) sq += __shfl_xor(sq, o);
        if (r == 0) atomicAdd(&hacc[h], sq);
    }
}

__global__ void k_init(float* __restrict__ hacc) {
    if (threadIdx.x < 4) hacc[threadIdx.x] = 0.f;
}

__global__ __launch_bounds__(256) void k_finalize(
    const float* __restrict__ y, const float* __restrict__ y_pred,
    const float* __restrict__ errors, const float* __restrict__ hacc,
    float* __restrict__ out)
{
    const int i = blockIdx.x*256 + threadIdx.x;
    if (i == 0)
        out[0] = (hacc[0]+hacc[1]+hacc[2]+hacc[3]) * (1.f/32768.f);
    if (i < 32768)      out[OFF_Y + i] = y[i];
    else if (i < 65536) out[OFF_YPRED + (i - 32768)] = y_pred[i - 32768];
    else if (i < 73728) { const int j = i - 65536; out[OFF_ERR + j] = errors[(size_t)j*4]; }
}

extern "C" void kernel_launch(void* const* d_in, const int* in_sizes, int n_in,
                              void* d_out, int out_size, void* d_ws, size_t ws_size,
                              hipStream_t stream)
{
    const float* Xt     = (const float*)d_in[0];
    const float* Xs     = (const float*)d_in[1];
    const float* errors = (const float*)d_in[2];
    const float* y      = (const float*)d_in[3];
    const float* y_pred = (const float*)d_in[4];
    const float* W1 = (const float*)d_in[5];   const float* b1 = (const float*)d_in[6];
    const float* W2 = (const float*)d_in[7];   const float* b2 = (const float*)d_in[8];
    const float* W3 = (const float*)d_in[9];   const float* b3 = (const float*)d_in[10];
    const float* W4 = (const float*)d_in[11];  const float* b4 = (const float*)d_in[12];
    const float* Wq = (const float*)d_in[13];  const float* bq = (const float*)d_in[14];
    const float* Wk = (const float*)d_in[15];  const float* bk = (const float*)d_in[16];
    const float* g_q    = (const float*)d_in[17];
    const float* beta_q = (const float*)d_in[18];
    const float* g_k    = (const float*)d_in[19];
    const float* beta_k = (const float*)d_in[20];

    float* out  = (float*)d_out;
    float* hacc = (float*)d_ws;
    const size_t SLAB = (size_t)16*2048*128;   // 4,194,304 elements
    float* qf = (float*)d_ws + 16;             // 16MB
    float* kf = qf + SLAB;                     // 16MB
    __hip_bfloat16* khi = (__hip_bfloat16*)(kf + SLAB);  // 8MB

    k_init<<<1, 64, 0, stream>>>(hacc);
    k_mlp<<<1024, 256, 0, stream>>>(Xt, Xs, W1,b1,W2,b2,W3,b3,W4,b4,
                                    Wq,bq,Wk,bk,g_q,beta_q,g_k,beta_k,
                                    qf, kf, khi);
    k_scores_topk<<<dim3(32,4,4), 256, 0, stream>>>(qf, kf, khi,
                                                    errors, y, y_pred, out, hacc);
    k_finalize<<<288, 256, 0, stream>>>(y, y_pred, errors, hacc, out);
}